// Round 1
// baseline (534.528 us; speedup 1.0000x reference)
//
#include <hip/hip_runtime.h>
#include <hip/hip_cooperative_groups.h>
#include <stdint.h>

namespace cg = cooperative_groups;

#define HH 224
#define WW 224
#define BB 4
#define PP 7          // seams per direction
#define SEG 28
#define BW 5
#define MM 11         // 2*BW+1

#define POS_INF_I 0x7F800000

#define RW 38
#define RH 14
#define RSTR 40

typedef const __attribute__((address_space(1))) unsigned int* gas_ptr;
typedef __attribute__((address_space(3))) unsigned int* las_ptr;
typedef unsigned long long ull;

// map-compose for 11-entry 4-bit-nibble maps packed in u64:  H[i] = F[G[i]]
__device__ inline ull mcompose(ull F, ull G) {
    ull H = 0ull;
#pragma unroll
    for (int i = 0; i < 11; ++i) {
        unsigned g = (unsigned)(G >> (4 * i)) & 15u;
        H |= ((F >> (4 * g)) & 15ull) << (4 * i);
    }
    return H;
}

// ---------------------------------------------------------------------------
// DP (verified absmax-0 logic, factored into device functions so the fused
// cooperative kernel and the fallback standalone kernel share one body)
// ---------------------------------------------------------------------------
__device__ __forceinline__ void dp_stage(const float* __restrict__ grad, float* gseg,
                                         int sid, int tid) {
    const int p   = sid % PP;
    const int dir = (sid / PP) & 1;
    const int b   = sid / (2 * PP);
    const int base = SEG * (p + 1);
    const float* gb = grad + b * (HH * WW);
    const int r  = tid >> 4;
    const int m  = tid & 15;
    const int sS = (dir == 0) ? WW : 1;
    const int sM = (dir == 0) ? 1  : WW;
    const float* src = gb + r * sS + (base - BW + m) * sM;
    const long stepBytes = (long)(4 * sS) * 4;
#pragma unroll 8
    for (int c = 0; c < 56; ++c) {
        __builtin_amdgcn_global_load_lds((gas_ptr)(const void*)src,
                                         (las_ptr)(void*)(&gseg[c * 64]), 4, 0, 0);
        src = (const float*)((const char*)src + stepBytes);
    }
}

__device__ __forceinline__ void dp_compute(int* __restrict__ coords_v,
                                           int* __restrict__ coords_h,
                                           const float* gseg, int sid, int tid) {
    const int l   = tid & 15;
    const int p   = sid % PP;
    const int dir = (sid / PP) & 1;
    const int b   = sid / (2 * PP);
    const int base = SEG * (p + 1);

    const float lane_add = (l < MM) ? 0.0f : __int_as_float(POS_INF_I);
    const float* gp = &gseg[l];

    unsigned wreg[16] = {};

#define DP_STEP(gval, ownb, jj_c)                                                       \
    {                                                                                   \
        float v1 = cost;                                                                \
        float v0 = __int_as_float(__builtin_amdgcn_update_dpp(                          \
            POS_INF_I, __float_as_int(cost), 0x111, 0xf, 0xf, false));                  \
        float v2 = __int_as_float(__builtin_amdgcn_update_dpp(                          \
            POS_INF_I, __float_as_int(cost), 0x101, 0xf, 0xf, false));                  \
        bool a01 = (v0 <= v1), a02 = (v0 <= v2), a12 = (v1 <= v2);                      \
        bool aa  = a01 && a02;                                                          \
        unsigned long long A   = __ballot(aa);                                          \
        unsigned long long C12 = __ballot(a12);                                         \
        unsigned long long B0 = ~A & C12;                                               \
        unsigned long long B1 = ~A & ~C12;                                              \
        float mv = aa ? v0 : (a12 ? v1 : v2);                                           \
        cost = mv - (gval) + lane_add;                                                  \
        unsigned wv = (unsigned)(B0 & 0x7FFull) | ((unsigned)(B1 & 0x7FFull) << 11);    \
        wreg[(jj_c)] = (ownb) ? wv : wreg[(jj_c)];                                      \
    }

    float cost = -gp[0] + lane_add;
    float buf[16], c0[16];
#pragma unroll
    for (int k = 0; k < 16; ++k) buf[k] = gp[(1 + k) * 16];
    for (int t = 0; t < 13; ++t) {
        const bool own = (tid == t);
#pragma unroll
        for (int k = 0; k < 16; ++k) c0[k] = buf[k];
#pragma unroll
        for (int k = 0; k < 16; ++k) buf[k] = gp[(16 * (t + 1) + 1 + k) * 16];
#pragma unroll
        for (int k = 0; k < 16; ++k) DP_STEP(c0[k], own, k)
    }
    {
        const bool own = (tid == 13);
#pragma unroll
        for (int k = 0; k < 15; ++k) DP_STEP(buf[k], own, k)
    }
#undef DP_STEP

    float bc = cost;
    int   bi = l;
#pragma unroll
    for (int mask = 1; mask < 16; mask <<= 1) {
        float oc = __shfl_xor(bc, mask, 16);
        int   oi = __shfl_xor(bi, mask, 16);
        if (oc < bc || (oc == bc && oi < bi)) { bc = oc; bi = oi; }
    }
    const int idx_last = bi;

    const int mcnt = (l < 13) ? 16 : ((l == 13) ? 15 : 0);
    const ull IDMAP = 0xA9876543210ull;
    ull L = IDMAP;
#pragma unroll
    for (int jj = 15; jj >= 0; --jj) {
        if (jj < mcnt) {
            unsigned ww = wreg[jj];
            ull M = 0ull;
#pragma unroll
            for (int i = 0; i < MM; ++i) {
                unsigned sel = ((ww >> i) & 1u) + 2u * ((ww >> (11 + i)) & 1u);
                M |= ((ull)(i + (int)sel - 1)) << (4 * i);
            }
            L = mcompose(M, L);
        }
    }
    ull I = L;
#pragma unroll
    for (int d = 1; d < 16; d <<= 1) {
        ull O = __shfl_down(I, d, 16);
        if (l + d < 16) I = mcompose(I, O);
    }
    ull R = __shfl_down(I, 1, 16);
    if (l == 15) R = IDMAP;

    int* cout = (dir == 0) ? coords_v : coords_h;
    if (tid == 15) cout[(b * HH + 223) * PP + p] = base + idx_last - BW;
    if (tid < 16) {
        unsigned v = (unsigned)(R >> (4 * idx_last)) & 15u;
#pragma unroll
        for (int jj = 15; jj >= 0; --jj) {
            if (jj < mcnt) {
                unsigned ww = wreg[jj];
                unsigned sel = ((ww >> v) & 1u) + 2u * ((ww >> (11 + v)) & 1u);
                v = v + sel - 1u;
                cout[(b * HH + (16 * l + jj)) * PP + p] = base + (int)v - BW;
            }
        }
    }
}

// ---------------------------------------------------------------------------
// labvote body: initial labels (analytic, 38x14 LDS region) + vote iter 1.
// Identical logic to the proven R8 kernel; LDS passed in by caller.
// ---------------------------------------------------------------------------
__device__ __forceinline__ void labvote_body(const int* __restrict__ cv,
                                             const int* __restrict__ ch,
                                             unsigned char* out8,
                                             int b, int GX0, int GY0, int t,
                                             unsigned char* lab, unsigned* bins) {
    for (int idx = t; idx < RW * RH; idx += 256) {
        int j = idx / RW, i = idx - j * RW;
        int gx = GX0 - 3 + i, gy = GY0 - 3 + j;
        if ((unsigned)gx < WW && (unsigned)gy < HH) {
            const int* cvp = cv + (b * HH + gy) * PP;
            const int* chp = ch + (b * WW + gx) * PP;
            int v = 0, h = 0;
#pragma unroll
            for (int q = 0; q < PP; ++q) { v += (cvp[q] <= gx); h += (chp[q] <= gy); }
            lab[j * RSTR + i] = (unsigned char)(v + 8 * h);
        }
    }
    __syncthreads();

    const int tx = t & 31, ty = t >> 5;
    const int gx = GX0 + tx, gy = GY0 + ty;
#pragma unroll
    for (int c = 0; c < 16; ++c) bins[c * 256 + t] = 0u;
#pragma unroll
    for (int dy = -3; dy <= 3; ++dy) {
        if ((unsigned)(gy + dy) >= HH) continue;
#pragma unroll
        for (int dx = -3; dx <= 3; ++dx) {
            if ((unsigned)(gx + dx) >= WW) continue;
            int lb = lab[(ty + 3 + dy) * RSTR + (tx + 3 + dx)];
            int ay = dy < 0 ? -dy : dy, ax = dx < 0 ? -dx : dx;
            int d = ay > ax ? ay : ax;
            unsigned wgt = (d <= 1) ? 3u : (unsigned)(4 - d);
            atomicAdd(&bins[(lb >> 2) * 256 + t], wgt << ((lb & 3) * 8));
        }
    }
    int best_s = 0, best_k = 0;
#pragma unroll
    for (int c = 0; c < 16; ++c) {
        unsigned wd = bins[c * 256 + t];
        if (wd) {
#pragma unroll
            for (int q = 0; q < 4; ++q) {
                int s = (int)((wd >> (q * 8)) & 255u);
                if (s > best_s) { best_s = s; best_k = c * 4 + q; }
            }
        }
    }
    out8[(b * HH + gy) * WW + gx] = (unsigned char)best_k;
}

// ---------------------------------------------------------------------------
// one vote for one pixel: packed row gather + uniform-window fast path,
// proven skip-OOB slow path. Returns argmax label.
// ---------------------------------------------------------------------------
__device__ __forceinline__ int vote_pixel(const unsigned char* __restrict__ img,
                                          int x, int y, int t, bool xedge,
                                          unsigned* __restrict__ bins) {
    ull rows[7];
    if (!xedge) {
        // interior-x: bytes x-3..x+3 in-image; 3 aligned dword loads/row
        const unsigned* img32 = (const unsigned*)img;
        const int o0 = x - 3;
#pragma unroll
        for (int dy = -3; dy <= 3; ++dy) {
            int yc = min(max(y + dy, 0), HH - 1);
            int o  = yc * WW + o0;
            int a  = o >> 2;
            int sh = (o & 3) * 8;
            unsigned d0 = img32[a], d1 = img32[a + 1], d2 = img32[a + 2];
            ull lo = ((ull)d1 << 32) | d0;
            ull row = lo >> sh;
            if (sh) row |= (ull)d2 << (64 - sh);
            rows[dy + 3] = row & 0x00FFFFFFFFFFFFFFull;
        }
    } else {
#pragma unroll
        for (int dy = -3; dy <= 3; ++dy) {
            int yc = min(max(y + dy, 0), HH - 1);
            ull row = 0ull;
#pragma unroll
            for (int dx = -3; dx <= 3; ++dx) {
                int xc = min(max(x + dx, 0), WW - 1);
                row |= (ull)img[yc * WW + xc] << (8 * (dx + 3));
            }
            rows[dy + 3] = row;
        }
    }

    const unsigned labc = (unsigned)((rows[3] >> 24) & 255u);   // dy=0, dx=0
    const ull rep = (ull)labc * 0x0001010101010101ull;
    bool uni = true;
#pragma unroll
    for (int k = 0; k < 7; ++k) uni = uni && (rows[k] == rep);
    if (uni) return (int)labc;   // exact: center is unique positive vote

#pragma unroll
    for (int c = 0; c < 16; ++c) bins[c * 256 + t] = 0u;
#pragma unroll
    for (int dy = -3; dy <= 3; ++dy) {
        if ((unsigned)(y + dy) >= (unsigned)HH) continue;
        ull row = rows[dy + 3];
        const int ay = dy < 0 ? -dy : dy;
#pragma unroll
        for (int dx = -3; dx <= 3; ++dx) {
            if ((unsigned)(x + dx) >= (unsigned)WW) continue;
            int lb = (int)((row >> (8 * (dx + 3))) & 255u);
            const int ax = dx < 0 ? -dx : dx;
            const int d = ay > ax ? ay : ax;
            const unsigned wgt = (d <= 1) ? 3u : (unsigned)(4 - d);
            atomicAdd(&bins[(lb >> 2) * 256 + t], wgt << ((lb & 3) * 8));
        }
    }
    int best_s = 0, best_k = 0;
#pragma unroll
    for (int c = 0; c < 16; ++c) {
        unsigned wd = bins[c * 256 + t];
        if (wd) {
#pragma unroll
            for (int q = 0; q < 4; ++q) {
                int s = (int)((wd >> (q * 8)) & 255u);
                if (s > best_s) { best_s = s; best_k = c * 4 + q; }
            }
        }
    }
    return best_k;
}

// ---------------------------------------------------------------------------
// FUSED cooperative kernel: dp (blocks 0..55, wave 0) -> grid sync ->
// labvote (v1) -> sync -> v2 -> sync -> v3 -> sync -> v4 -> sync -> v5(out32).
// Occupancy: LDS 16944 B -> 9 blk/CU; __launch_bounds__(256,4) caps VGPR<=128
// -> >=4 blk/CU co-resident -> 1024 >= 784 blocks. Cooperative launch
// validates this at launch time.
// ---------------------------------------------------------------------------
__global__ __launch_bounds__(256, 4) void fused_kernel(const float* __restrict__ grad,
                                                       int* __restrict__ cv,
                                                       int* __restrict__ ch,
                                                       unsigned char* laD,
                                                       unsigned char* laW,
                                                       int* out32) {
    __shared__ __align__(16) union {
        float gseg[225 * 16];                                   // 14400 B (dp phase)
        struct { unsigned char lab[RH * RSTR]; unsigned bins[16 * 256]; } v;  // 16944 B
    } sm;

    cg::grid_group grid = cg::this_grid();
    const int tid = threadIdx.x;
    const int bid = blockIdx.x;

    // ---- phase 0: DP seams (blocks 0..55, wave 0 only — identical to standalone)
    if (bid < 56) {
        if (tid < 64) dp_stage(grad, sm.gseg, bid, tid);
        __syncthreads();
        if (tid < 64) dp_compute(cv, ch, sm.gseg, bid, tid);
    }
    grid.sync();

    // ---- tile mapping (matches old grid (7,28,4) x (32,8))
    const int bx = bid % 7;
    const int by = (bid / 7) % 28;
    const int b  = bid / 196;
    const int GX0 = bx * 32, GY0 = by * 8;
    const int t  = tid;
    const int tx = t & 31, ty = t >> 5;
    const int x = GX0 + tx, y = GY0 + ty;
    const int o = (b * HH + y) * WW + x;
    const bool xedge = (bx == 0) || (bx == (WW / 32 - 1));

    // ---- phase 1: initial labels + vote 1 -> laD
    labvote_body(cv, ch, laD, b, GX0, GY0, t, sm.v.lab, sm.v.bins);

    // ---- phases 2..5: ping-pong votes with grid-wide sync between them
    grid.sync();
    laW[o] = (unsigned char)vote_pixel(laD + b * (HH * WW), x, y, t, xedge, sm.v.bins);
    grid.sync();
    laD[o] = (unsigned char)vote_pixel(laW + b * (HH * WW), x, y, t, xedge, sm.v.bins);
    grid.sync();
    laW[o] = (unsigned char)vote_pixel(laD + b * (HH * WW), x, y, t, xedge, sm.v.bins);
    grid.sync();
    out32[o] = vote_pixel(laW + b * (HH * WW), x, y, t, xedge, sm.v.bins);
}

// ---------------------------------------------------------------------------
// Fallback standalone kernels (same proven bodies) — used only if the
// cooperative launch is rejected (e.g. capture/occupancy validation).
// ---------------------------------------------------------------------------
__global__ __launch_bounds__(64) void dp_kernel(const float* __restrict__ grad,
                                                int* __restrict__ coords_v,
                                                int* __restrict__ coords_h) {
    __shared__ __align__(16) float gseg[225 * 16];
    dp_stage(grad, gseg, blockIdx.x, threadIdx.x);
    __syncthreads();
    dp_compute(coords_v, coords_h, gseg, blockIdx.x, threadIdx.x);
}

__global__ __launch_bounds__(256) void labvote_kernel(const int* __restrict__ cv,
                                                      const int* __restrict__ ch,
                                                      unsigned char* __restrict__ out8) {
    __shared__ unsigned char lab[RH * RSTR];
    __shared__ unsigned bins[16 * 256];
    labvote_body(cv, ch, out8, blockIdx.z, blockIdx.x * 32, blockIdx.y * 8,
                 threadIdx.y * 32 + threadIdx.x, lab, bins);
}

__global__ __launch_bounds__(256) void vote_kernel(const unsigned char* __restrict__ in,
                                                   unsigned char* __restrict__ out8,
                                                   int* __restrict__ out32) {
    __shared__ unsigned bins[16 * 256];
    const int tx = threadIdx.x, ty = threadIdx.y;
    const int t  = ty * 32 + tx;
    const int x  = blockIdx.x * 32 + tx;
    const int y  = blockIdx.y * 8 + ty;
    const int b  = blockIdx.z;
    const bool xedge = (blockIdx.x == 0) || (blockIdx.x == (WW / 32 - 1));
    int best_k = vote_pixel(in + b * (HH * WW), x, y, t, xedge, bins);
    int o = (b * HH + y) * WW + x;
    if (out8)  out8[o]  = (unsigned char)best_k;
    if (out32) out32[o] = best_k;
}

// ---------------------------------------------------------------------------
extern "C" void kernel_launch(void* const* d_in, const int* in_sizes, int n_in,
                              void* d_out, int out_size, void* d_ws, size_t ws_size,
                              hipStream_t stream) {
    (void)in_sizes; (void)n_in; (void)out_size; (void)ws_size;
    const float* grad = (const float*)d_in[0];
    int* out = (int*)d_out;
    char* ws = (char*)d_ws;

    int* cv = (int*)(ws);                               // 25088 B
    int* ch = (int*)(ws + 25088);                       // 25088 B
    unsigned char* laW = (unsigned char*)(ws + 50176);  // ping (ws)
    unsigned char* laD = (unsigned char*)d_out;         // pong (inside d_out)

    void* args[6];
    args[0] = (void*)&grad;
    args[1] = (void*)&cv;
    args[2] = (void*)&ch;
    args[3] = (void*)&laD;
    args[4] = (void*)&laW;
    args[5] = (void*)&out;

    hipError_t err = hipLaunchCooperativeKernel(fused_kernel, dim3(784, 1, 1),
                                                dim3(256, 1, 1), args, 0, stream);
    if (err != hipSuccess) {
        // fallback: proven 6-launch pipeline (identical bodies)
        dp_kernel<<<56, 64, 0, stream>>>(grad, cv, ch);
        dim3 g(WW / 32, HH / 8, BB), blk(32, 8, 1);
        labvote_kernel<<<g, blk, 0, stream>>>(cv, ch, laD);        // v1 -> laD
        vote_kernel<<<g, blk, 0, stream>>>(laD, laW, nullptr);     // v2 -> laW
        vote_kernel<<<g, blk, 0, stream>>>(laW, laD, nullptr);     // v3 -> laD
        vote_kernel<<<g, blk, 0, stream>>>(laD, laW, nullptr);     // v4 -> laW
        vote_kernel<<<g, blk, 0, stream>>>(laW, nullptr, out);     // v5 -> int out
    }
}

// Round 2
// 185.819 us; speedup vs baseline: 2.8766x; 2.8766x over previous
//
#include <hip/hip_runtime.h>
#include <stdint.h>

#define HH 224
#define WW 224
#define BB 4
#define PP 7          // seams per direction
#define SEG 28
#define BW 5
#define MM 11         // 2*BW+1

#define POS_INF_I 0x7F800000

// mega-kernel region: 32x8 output tile + halo 15 (5 iterations x radius 3)
#define RGW 62
#define RGH 38
#define RSTRIDE 64

typedef const __attribute__((address_space(1))) unsigned int* gas_ptr;
typedef __attribute__((address_space(3))) unsigned int* las_ptr;
typedef unsigned long long ull;

// map-compose for 11-entry 4-bit-nibble maps packed in u64:  H[i] = F[G[i]]
__device__ inline ull mcompose(ull F, ull G) {
    ull H = 0ull;
#pragma unroll
    for (int i = 0; i < 11; ++i) {
        unsigned g = (unsigned)(G >> (4 * i)) & 15u;
        H |= ((F >> (4 * g)) & 15ull) << (4 * i);
    }
    return H;
}

// ---------------------------------------------------------------------------
// DP kernel (verified absmax-0, unchanged)
// ---------------------------------------------------------------------------
__global__ __launch_bounds__(64) void dp_kernel(const float* __restrict__ grad,
                                                int* __restrict__ coords_v,
                                                int* __restrict__ coords_h) {
    __shared__ __align__(16) float gseg[225 * 16];

    const int tid = threadIdx.x;
    const int l   = tid & 15;
    const int sid = blockIdx.x;
    const int p   = sid % PP;
    const int dir = (sid / PP) & 1;
    const int b   = sid / (2 * PP);
    const int base = SEG * (p + 1);
    const float* gb = grad + b * (HH * WW);

    {
        const int r  = tid >> 4;
        const int m  = tid & 15;
        const int sS = (dir == 0) ? WW : 1;
        const int sM = (dir == 0) ? 1  : WW;
        const float* src = gb + r * sS + (base - BW + m) * sM;
        const long stepBytes = (long)(4 * sS) * 4;
#pragma unroll 8
        for (int c = 0; c < 56; ++c) {
            __builtin_amdgcn_global_load_lds((gas_ptr)(const void*)src,
                                             (las_ptr)(void*)(&gseg[c * 64]), 4, 0, 0);
            src = (const float*)((const char*)src + stepBytes);
        }
    }
    __syncthreads();

    const float lane_add = (l < MM) ? 0.0f : __int_as_float(POS_INF_I);
    const float* gp = &gseg[l];

    unsigned wreg[16] = {};

#define DP_STEP(gval, ownb, jj_c)                                                       \
    {                                                                                   \
        float v1 = cost;                                                                \
        float v0 = __int_as_float(__builtin_amdgcn_update_dpp(                          \
            POS_INF_I, __float_as_int(cost), 0x111, 0xf, 0xf, false));                  \
        float v2 = __int_as_float(__builtin_amdgcn_update_dpp(                          \
            POS_INF_I, __float_as_int(cost), 0x101, 0xf, 0xf, false));                  \
        bool a01 = (v0 <= v1), a02 = (v0 <= v2), a12 = (v1 <= v2);                      \
        bool aa  = a01 && a02;                                                          \
        unsigned long long A   = __ballot(aa);                                          \
        unsigned long long C12 = __ballot(a12);                                         \
        unsigned long long B0 = ~A & C12;                                               \
        unsigned long long B1 = ~A & ~C12;                                              \
        float mv = aa ? v0 : (a12 ? v1 : v2);                                           \
        cost = mv - (gval) + lane_add;                                                  \
        unsigned wv = (unsigned)(B0 & 0x7FFull) | ((unsigned)(B1 & 0x7FFull) << 11);    \
        wreg[(jj_c)] = (ownb) ? wv : wreg[(jj_c)];                                      \
    }

    float cost = -gp[0] + lane_add;
    float buf[16], c0[16];
#pragma unroll
    for (int k = 0; k < 16; ++k) buf[k] = gp[(1 + k) * 16];
    for (int t = 0; t < 13; ++t) {
        const bool own = (tid == t);
#pragma unroll
        for (int k = 0; k < 16; ++k) c0[k] = buf[k];
#pragma unroll
        for (int k = 0; k < 16; ++k) buf[k] = gp[(16 * (t + 1) + 1 + k) * 16];
#pragma unroll
        for (int k = 0; k < 16; ++k) DP_STEP(c0[k], own, k)
    }
    {
        const bool own = (tid == 13);
#pragma unroll
        for (int k = 0; k < 15; ++k) DP_STEP(buf[k], own, k)
    }
#undef DP_STEP

    float bc = cost;
    int   bi = l;
#pragma unroll
    for (int mask = 1; mask < 16; mask <<= 1) {
        float oc = __shfl_xor(bc, mask, 16);
        int   oi = __shfl_xor(bi, mask, 16);
        if (oc < bc || (oc == bc && oi < bi)) { bc = oc; bi = oi; }
    }
    const int idx_last = bi;

    const int mcnt = (l < 13) ? 16 : ((l == 13) ? 15 : 0);
    const ull IDMAP = 0xA9876543210ull;
    ull L = IDMAP;
#pragma unroll
    for (int jj = 15; jj >= 0; --jj) {
        if (jj < mcnt) {
            unsigned ww = wreg[jj];
            ull M = 0ull;
#pragma unroll
            for (int i = 0; i < MM; ++i) {
                unsigned sel = ((ww >> i) & 1u) + 2u * ((ww >> (11 + i)) & 1u);
                M |= ((ull)(i + (int)sel - 1)) << (4 * i);
            }
            L = mcompose(M, L);
        }
    }
    ull I = L;
#pragma unroll
    for (int d = 1; d < 16; d <<= 1) {
        ull O = __shfl_down(I, d, 16);
        if (l + d < 16) I = mcompose(I, O);
    }
    ull R = __shfl_down(I, 1, 16);
    if (l == 15) R = IDMAP;

    int* cout = (dir == 0) ? coords_v : coords_h;
    if (tid == 15) cout[(b * HH + 223) * PP + p] = base + idx_last - BW;
    if (tid < 16) {
        unsigned v = (unsigned)(R >> (4 * idx_last)) & 15u;
#pragma unroll
        for (int jj = 15; jj >= 0; --jj) {
            if (jj < mcnt) {
                unsigned ww = wreg[jj];
                unsigned sel = ((ww >> v) & 1u) + 2u * ((ww >> (11 + v)) & 1u);
                v = v + sel - 1u;
                cout[(b * HH + (16 * l + jj)) * PP + p] = base + (int)v - BW;
            }
        }
    }
}

// ---------------------------------------------------------------------------
// mega kernel helpers
// ---------------------------------------------------------------------------

// slow vote: per-thread packed byte bins (column t, thread-private -> plain adds).
// Sentinel 255 = out-of-image, skipped (== reference's zero-padded conv).
// Max weight sum per window = 9*3+16*2+24*1 = 83 < 255, bytes can't overflow.
__device__ __forceinline__ int slow_vote(const ull* rows, int t, unsigned* bins) {
#pragma unroll
    for (int c = 0; c < 16; ++c) bins[c * 256 + t] = 0u;
#pragma unroll
    for (int dy = 0; dy < 7; ++dy) {
        ull row = rows[dy];
        const int ay = dy < 3 ? 3 - dy : dy - 3;
#pragma unroll
        for (int dx = 0; dx < 7; ++dx) {
            unsigned lb = (unsigned)((row >> (8 * dx)) & 255u);
            if (lb != 255u) {
                const int ax = dx < 3 ? 3 - dx : dx - 3;
                const int d = ay > ax ? ay : ax;
                const unsigned wgt = (d <= 1) ? 3u : (unsigned)(4 - d);
                bins[(lb >> 2) * 256 + t] += wgt << ((lb & 3) * 8);
            }
        }
    }
    int best_s = 0, best_k = 0;
#pragma unroll
    for (int c = 0; c < 16; ++c) {
        unsigned wd = bins[c * 256 + t];
        if (wd) {
#pragma unroll
            for (int q = 0; q < 4; ++q) {
                int s = (int)((wd >> (q * 8)) & 255u);
                if (s > best_s) { best_s = s; best_k = c * 4 + q; }
            }
        }
    }
    return best_k;
}

// gather the 7x7 window rows (7 bytes each) around region coord (px,py) from an
// LDS label buffer (stride RSTRIDE, 8B-aligned reads; garbage beyond byte 61
// of each row is masked off by the 56-bit row mask).
__device__ __forceinline__ void gather_rows(const unsigned char* src, int px, int py,
                                            ull* rows) {
#pragma unroll
    for (int dy = 0; dy < 7; ++dy) {
        int o  = (py + dy - 3) * RSTRIDE + (px - 3);
        int a8 = o & ~7;
        int sh = (o & 7) * 8;
        ull lo = *reinterpret_cast<const ull*>(src + a8);
        ull hi = *reinterpret_cast<const ull*>(src + a8 + 8);
        ull row = lo >> sh;
        if (sh) row |= hi << (64 - sh);
        rows[dy] = row & 0x00FFFFFFFFFFFFFFull;
    }
}

// one vote iteration over the region with margin MARG (valid halo shrinks by 3).
// OOB (sentinel) pixels propagate 255; uniform-window fast path is exact
// (all clamped bytes == center <= 63 implies no sentinel and unique max).
template<int MARG>
__device__ __forceinline__ void vote_iter(const unsigned char* src, unsigned char* dst,
                                          int t, unsigned* bins) {
    constexpr int WK = RGW - 2 * MARG;
    constexpr int HK = RGH - 2 * MARG;
    for (int idx = t; idx < WK * HK; idx += 256) {
        int py = MARG + idx / WK;
        int px = MARG + idx - (idx / WK) * WK;
        int center = py * RSTRIDE + px;
        unsigned cl = src[center];
        unsigned char res;
        if (cl == 255u) {
            res = 255;
        } else {
            ull rows[7];
            gather_rows(src, px, py, rows);
            const ull rep = (ull)cl * 0x0001010101010101ull;
            bool uni = true;
#pragma unroll
            for (int k = 0; k < 7; ++k) uni = uni && (rows[k] == rep);
            res = uni ? (unsigned char)cl : (unsigned char)slow_vote(rows, t, bins);
        }
        dst[center] = res;
    }
}

// ---------------------------------------------------------------------------
// MEGA kernel: initial labels (analytic from cv/ch) + ALL 5 vote iterations
// in LDS via halo recomputation. No intermediate global traffic, no grid sync.
// Grid (7,28,4) x 256. LDS = 16384 + 2*2432 + 1064 + 1736 = 24048 B
// -> 6 blocks/CU >= 3.06 needed for full residency.
// ---------------------------------------------------------------------------
__global__ __launch_bounds__(256) void mega_kernel(const int* __restrict__ cv,
                                                   const int* __restrict__ ch,
                                                   int* __restrict__ out32) {
    __shared__ __align__(16) unsigned bins[16 * 256];
    __shared__ __align__(16) unsigned char labA[RGH * RSTRIDE];
    __shared__ __align__(16) unsigned char labB[RGH * RSTRIDE];
    __shared__ int cvs[RGH * PP];
    __shared__ int chs[RGW * PP];

    const int t  = threadIdx.x;
    const int b  = blockIdx.z;
    const int ox = blockIdx.x * 32 - 15;
    const int oy = blockIdx.y * 8 - 15;

    // ---- stage the cv/ch slices this region needs (L2-resident, contiguous)
    for (int idx = t; idx < RGH * PP; idx += 256) {
        int gy = oy + idx / PP;
        cvs[idx] = ((unsigned)gy < HH) ? cv[(b * HH + gy) * PP + idx % PP] : 0x7fffffff;
    }
    for (int idx = t; idx < RGW * PP; idx += 256) {
        int gx = ox + idx / PP;
        chs[idx] = ((unsigned)gx < WW) ? ch[(b * WW + gx) * PP + idx % PP] : 0x7fffffff;
    }
    __syncthreads();

    // ---- initial labels over full 62x38 region (analytic; OOB -> sentinel 255)
    for (int idx = t; idx < RGW * RGH; idx += 256) {
        int py = idx / RGW;
        int px = idx - py * RGW;
        int gx = ox + px, gy = oy + py;
        unsigned char lbl = 255;
        if ((unsigned)gx < WW && (unsigned)gy < HH) {
            int v = 0, h = 0;
#pragma unroll
            for (int q = 0; q < PP; ++q) {
                v += (cvs[py * PP + q] <= gx);
                h += (chs[px * PP + q] <= gy);
            }
            lbl = (unsigned char)(v + 8 * h);
        }
        labA[py * RSTRIDE + px] = lbl;
    }
    __syncthreads();

    // ---- 4 ping-pong vote iterations with shrinking valid region
    vote_iter<3>(labA, labB, t, bins);  __syncthreads();   // v1: 56x32
    vote_iter<6>(labB, labA, t, bins);  __syncthreads();   // v2: 50x26
    vote_iter<9>(labA, labB, t, bins);  __syncthreads();   // v3: 44x20
    vote_iter<12>(labB, labA, t, bins); __syncthreads();   // v4: 38x14

    // ---- final iteration: 32x8 output tile, one pixel per thread, int32 out
    {
        const int px = 15 + (t & 31);
        const int py = 15 + (t >> 5);
        unsigned cl = labA[py * RSTRIDE + px];   // in-image by construction
        int res;
        ull rows[7];
        gather_rows(labA, px, py, rows);
        const ull rep = (ull)cl * 0x0001010101010101ull;
        bool uni = true;
#pragma unroll
        for (int k = 0; k < 7; ++k) uni = uni && (rows[k] == rep);
        res = uni ? (int)cl : slow_vote(rows, t, bins);
        const int gx = ox + px, gy = oy + py;
        out32[(b * HH + gy) * WW + gx] = res;
    }
}

// ---------------------------------------------------------------------------
extern "C" void kernel_launch(void* const* d_in, const int* in_sizes, int n_in,
                              void* d_out, int out_size, void* d_ws, size_t ws_size,
                              hipStream_t stream) {
    (void)in_sizes; (void)n_in; (void)out_size; (void)ws_size;
    const float* grad = (const float*)d_in[0];
    int* out = (int*)d_out;
    char* ws = (char*)d_ws;

    int* cv = (int*)(ws);            // 25088 B
    int* ch = (int*)(ws + 25088);    // 25088 B

    dp_kernel<<<56, 64, 0, stream>>>(grad, cv, ch);

    dim3 grid(WW / 32, HH / 8, BB), blk(256, 1, 1);
    mega_kernel<<<grid, blk, 0, stream>>>(cv, ch, out);
}

// Round 3
// 124.346 us; speedup vs baseline: 4.2987x; 1.4944x over previous
//
#include <hip/hip_runtime.h>
#include <stdint.h>

#define HH 224
#define WW 224
#define BB 4
#define PP 7          // seams per direction
#define SEG 28
#define BW 5
#define MM 11         // 2*BW+1

#define POS_INF_I 0x7F800000

typedef const __attribute__((address_space(1))) unsigned int* gas_ptr;
typedef __attribute__((address_space(3))) unsigned int* las_ptr;
typedef unsigned long long ull;

// map-compose for 11-entry 4-bit-nibble maps packed in u64:  H[i] = F[G[i]]
__device__ inline ull mcompose(ull F, ull G) {
    ull H = 0ull;
#pragma unroll
    for (int i = 0; i < 11; ++i) {
        unsigned g = (unsigned)(G >> (4 * i)) & 15u;
        H |= ((F >> (4 * g)) & 15ull) << (4 * i);
    }
    return H;
}

// ---------------------------------------------------------------------------
// DP kernel (verified absmax 0 — unchanged from round 0)
// ---------------------------------------------------------------------------
__global__ __launch_bounds__(64) void dp_kernel(const float* __restrict__ grad,
                                                int* __restrict__ coords_v,
                                                int* __restrict__ coords_h) {
    __shared__ __align__(16) float gseg[225 * 16];

    const int tid = threadIdx.x;
    const int l   = tid & 15;
    const int sid = blockIdx.x;
    const int p   = sid % PP;
    const int dir = (sid / PP) & 1;
    const int b   = sid / (2 * PP);
    const int base = SEG * (p + 1);
    const float* gb = grad + b * (HH * WW);

    {
        const int r  = tid >> 4;
        const int m  = tid & 15;
        const int sS = (dir == 0) ? WW : 1;
        const int sM = (dir == 0) ? 1  : WW;
        const float* src = gb + r * sS + (base - BW + m) * sM;
        const long stepBytes = (long)(4 * sS) * 4;
#pragma unroll 8
        for (int c = 0; c < 56; ++c) {
            __builtin_amdgcn_global_load_lds((gas_ptr)(const void*)src,
                                             (las_ptr)(void*)(&gseg[c * 64]), 4, 0, 0);
            src = (const float*)((const char*)src + stepBytes);
        }
    }
    __syncthreads();

    const float lane_add = (l < MM) ? 0.0f : __int_as_float(POS_INF_I);
    const float* gp = &gseg[l];

    unsigned wreg[16] = {};

#define DP_STEP(gval, ownb, jj_c)                                                       \
    {                                                                                   \
        float v1 = cost;                                                                \
        float v0 = __int_as_float(__builtin_amdgcn_update_dpp(                          \
            POS_INF_I, __float_as_int(cost), 0x111, 0xf, 0xf, false));                  \
        float v2 = __int_as_float(__builtin_amdgcn_update_dpp(                          \
            POS_INF_I, __float_as_int(cost), 0x101, 0xf, 0xf, false));                  \
        bool a01 = (v0 <= v1), a02 = (v0 <= v2), a12 = (v1 <= v2);                      \
        bool aa  = a01 && a02;                                                          \
        unsigned long long A   = __ballot(aa);                                          \
        unsigned long long C12 = __ballot(a12);                                         \
        unsigned long long B0 = ~A & C12;                                               \
        unsigned long long B1 = ~A & ~C12;                                              \
        float mv = aa ? v0 : (a12 ? v1 : v2);                                           \
        cost = mv - (gval) + lane_add;                                                  \
        unsigned wv = (unsigned)(B0 & 0x7FFull) | ((unsigned)(B1 & 0x7FFull) << 11);    \
        wreg[(jj_c)] = (ownb) ? wv : wreg[(jj_c)];                                      \
    }

    float cost = -gp[0] + lane_add;
    float buf[16], c0[16];
#pragma unroll
    for (int k = 0; k < 16; ++k) buf[k] = gp[(1 + k) * 16];
    for (int t = 0; t < 13; ++t) {
        const bool own = (tid == t);
#pragma unroll
        for (int k = 0; k < 16; ++k) c0[k] = buf[k];
#pragma unroll
        for (int k = 0; k < 16; ++k) buf[k] = gp[(16 * (t + 1) + 1 + k) * 16];
#pragma unroll
        for (int k = 0; k < 16; ++k) DP_STEP(c0[k], own, k)
    }
    {
        const bool own = (tid == 13);
#pragma unroll
        for (int k = 0; k < 15; ++k) DP_STEP(buf[k], own, k)
    }
#undef DP_STEP

    float bc = cost;
    int   bi = l;
#pragma unroll
    for (int mask = 1; mask < 16; mask <<= 1) {
        float oc = __shfl_xor(bc, mask, 16);
        int   oi = __shfl_xor(bi, mask, 16);
        if (oc < bc || (oc == bc && oi < bi)) { bc = oc; bi = oi; }
    }
    const int idx_last = bi;

    const int mcnt = (l < 13) ? 16 : ((l == 13) ? 15 : 0);
    const ull IDMAP = 0xA9876543210ull;
    ull L = IDMAP;
#pragma unroll
    for (int jj = 15; jj >= 0; --jj) {
        if (jj < mcnt) {
            unsigned ww = wreg[jj];
            ull M = 0ull;
#pragma unroll
            for (int i = 0; i < MM; ++i) {
                unsigned sel = ((ww >> i) & 1u) + 2u * ((ww >> (11 + i)) & 1u);
                M |= ((ull)(i + (int)sel - 1)) << (4 * i);
            }
            L = mcompose(M, L);
        }
    }
    ull I = L;
#pragma unroll
    for (int d = 1; d < 16; d <<= 1) {
        ull O = __shfl_down(I, d, 16);
        if (l + d < 16) I = mcompose(I, O);
    }
    ull R = __shfl_down(I, 1, 16);
    if (l == 15) R = IDMAP;

    int* cout = (dir == 0) ? coords_v : coords_h;
    if (tid == 15) cout[(b * HH + 223) * PP + p] = base + idx_last - BW;
    if (tid < 16) {
        unsigned v = (unsigned)(R >> (4 * idx_last)) & 15u;
#pragma unroll
        for (int jj = 15; jj >= 0; --jj) {
            if (jj < mcnt) {
                unsigned ww = wreg[jj];
                unsigned sel = ((ww >> v) & 1u) + 2u * ((ww >> (11 + v)) & 1u);
                v = v + sel - 1u;
                cout[(b * HH + (16 * l + jj)) * PP + p] = base + (int)v - BW;
            }
        }
    }
}

// ---------------------------------------------------------------------------
// labvote: initial labels (analytic, 38x14 LDS region) + vote iteration 1.
// Unchanged from round 0 (proven). Grid (7,28,4) x (32,8).
// ---------------------------------------------------------------------------
#define RW 38
#define RH 14
#define RSTR 40

__global__ __launch_bounds__(256) void labvote_kernel(const int* __restrict__ cv,
                                                      const int* __restrict__ ch,
                                                      unsigned char* __restrict__ out8) {
    __shared__ unsigned char lab[RH * RSTR];
    __shared__ unsigned bins[16 * 256];
    const int tx = threadIdx.x, ty = threadIdx.y;
    const int t  = ty * 32 + tx;
    const int b  = blockIdx.z;
    const int GX0 = blockIdx.x * 32, GY0 = blockIdx.y * 8;

    for (int idx = t; idx < RW * RH; idx += 256) {
        int j = idx / RW, i = idx - j * RW;
        int gx = GX0 - 3 + i, gy = GY0 - 3 + j;
        if ((unsigned)gx < WW && (unsigned)gy < HH) {
            const int* cvp = cv + (b * HH + gy) * PP;
            const int* chp = ch + (b * WW + gx) * PP;
            int v = 0, h = 0;
#pragma unroll
            for (int q = 0; q < PP; ++q) { v += (cvp[q] <= gx); h += (chp[q] <= gy); }
            lab[j * RSTR + i] = (unsigned char)(v + 8 * h);
        }
    }
    __syncthreads();

    const int gx = GX0 + tx, gy = GY0 + ty;
#pragma unroll
    for (int c = 0; c < 16; ++c) bins[c * 256 + t] = 0u;
#pragma unroll
    for (int dy = -3; dy <= 3; ++dy) {
        if ((unsigned)(gy + dy) >= HH) continue;
#pragma unroll
        for (int dx = -3; dx <= 3; ++dx) {
            if ((unsigned)(gx + dx) >= WW) continue;
            int lb = lab[(ty + 3 + dy) * RSTR + (tx + 3 + dx)];
            int ay = dy < 0 ? -dy : dy, ax = dx < 0 ? -dx : dx;
            int d = ay > ax ? ay : ax;
            unsigned wgt = (d <= 1) ? 3u : (unsigned)(4 - d);
            atomicAdd(&bins[(lb >> 2) * 256 + t], wgt << ((lb & 3) * 8));
        }
    }
    int best_s = 0, best_k = 0;
#pragma unroll
    for (int c = 0; c < 16; ++c) {
        unsigned wd = bins[c * 256 + t];
        if (wd) {
#pragma unroll
            for (int q = 0; q < 4; ++q) {
                int s = (int)((wd >> (q * 8)) & 255u);
                if (s > best_s) { best_s = s; best_k = c * 4 + q; }
            }
        }
    }
    out8[(b * HH + gy) * WW + gx] = (unsigned char)best_k;
}

// ---------------------------------------------------------------------------
// Proven LDS-bins slow path (round-0 logic, verbatim) — now the FALLBACK.
// ---------------------------------------------------------------------------
__device__ __forceinline__ int slow_vote_bins(const ull* rows, int x, int y, int t,
                                              unsigned* __restrict__ bins) {
#pragma unroll
    for (int c = 0; c < 16; ++c) bins[c * 256 + t] = 0u;
#pragma unroll
    for (int dy = -3; dy <= 3; ++dy) {
        if ((unsigned)(y + dy) >= (unsigned)HH) continue;
        ull row = rows[dy + 3];
        const int ay = dy < 0 ? -dy : dy;
#pragma unroll
        for (int dx = -3; dx <= 3; ++dx) {
            if ((unsigned)(x + dx) >= (unsigned)WW) continue;
            int lb = (int)((row >> (8 * (dx + 3))) & 255u);
            const int ax = dx < 0 ? -dx : dx;
            const int d = ay > ax ? ay : ax;
            const unsigned wgt = (d <= 1) ? 3u : (unsigned)(4 - d);
            atomicAdd(&bins[(lb >> 2) * 256 + t], wgt << ((lb & 3) * 8));
        }
    }
    int best_s = 0, best_k = 0;
#pragma unroll
    for (int c = 0; c < 16; ++c) {
        unsigned wd = bins[c * 256 + t];
        if (wd) {
#pragma unroll
            for (int q = 0; q < 4; ++q) {
                int s = (int)((wd >> (q * 8)) & 255u);
                if (s > best_s) { best_s = s; best_k = c * 4 + q; }
            }
        }
    }
    return best_k;
}

// ---------------------------------------------------------------------------
// Register-only SWAR slow path: score center + up to 3 discovered candidates
// via exact per-byte equality masks and multiply dot-products. Positional
// validity via vmx (x) + per-row y guard — exact zero-padding semantics
// (clamped duplicate bytes in rows are never counted). Fallback to the proven
// bins path if >4 distinct labels appear in a window.
// ---------------------------------------------------------------------------
#define SW_K1   0x0001010101010101ull
#define SW_HI7  0x0080808080808080ull
#define SW_LO7  0x007F7F7F7F7F7F7Full
#define SW_W1   0x0001020303030201ull   /* rows |dy|<=1: [1,2,3,3,3,2,1] */
#define SW_W2   0x0001020202020201ull   /* rows |dy|==2: [1,2,2,2,2,2,1] */

// exact per-byte zero markers (0x80 where byte == 0), bytes 0..6 only.
// requires byte7 of xv to be 0 (rows are 56-bit-masked; reps have byte7=0).
__device__ __forceinline__ ull sw_zm(ull xv) {
    return (~(((xv & SW_LO7) + SW_LO7) | xv)) & SW_HI7;
}
// dot of marker-vector (0x80 per match) with symmetric weight row W.
// byte-6 coefficient of (m01 * W) = sum_i m01[i] * W[6-i]; max 15, no carries.
__device__ __forceinline__ int sw_dotm(ull m, ull W) {
    return (int)((((m >> 7) * W) >> 48) & 0xFFull);
}

__device__ __forceinline__ int swar_or_bins(const ull* rows, int x, int y,
                                            unsigned cl, int t,
                                            unsigned* __restrict__ bins) {
    // x-validity: marker at byte dx iff 0 <= x+dx-3 < WW
    ull vmx = SW_HI7;
    if (x < 3)   vmx &= (~0ull) << (8 * (3 - x));
    if (x > 220) vmx &= (1ull << (8 * (227 - x))) - 1ull;

    unsigned c1 = 254u, c2 = 254u, c3 = 254u;   // 254 = empty slot (never a label)
    int s0 = 0, s1 = 0, s2 = 0, s3 = 0;
    bool ovf = false;
    const ull rep0 = (ull)cl * SW_K1;

#pragma unroll
    for (int r = 0; r < 7; ++r) {
        if ((unsigned)(y + r - 3) >= (unsigned)HH) continue;
        const ull row = rows[r];
        const int ay   = r < 3 ? 3 - r : r - 3;        // compile-time per r
        const bool POPC = (ay == 3);                    // weight row all-ones
        const ull W    = (ay <= 1) ? SW_W1 : SW_W2;

        ull e0 = sw_zm(row ^ rep0) & vmx;
        ull e1 = sw_zm(row ^ ((ull)c1 * SW_K1)) & vmx;
        ull e2 = sw_zm(row ^ ((ull)c2 * SW_K1)) & vmx;
        ull e3 = sw_zm(row ^ ((ull)c3 * SW_K1)) & vmx;
        s0 += POPC ? __popcll(e0) : sw_dotm(e0, W);
        s1 += POPC ? __popcll(e1) : sw_dotm(e1, W);
        s2 += POPC ? __popcll(e2) : sw_dotm(e2, W);
        s3 += POPC ? __popcll(e3) : sw_dotm(e3, W);

        // discover new candidates among still-unexplained valid bytes.
        // row-major discovery => a new candidate has no matches in earlier
        // rows (they would have been discovered there), so single-pass
        // accumulation is exact.
        ull rem = vmx & ~(e0 | e1 | e2 | e3);
        for (int it = 0; it < 3 && rem; ++it) {
            int pos = (int)__builtin_ctzll(rem);        // marker bit = 8k+7
            unsigned nb = (unsigned)((row >> (pos - 7)) & 255u);
            ull en = sw_zm(row ^ ((ull)nb * SW_K1)) & vmx;
            int dn = POPC ? __popcll(en) : sw_dotm(en, W);
            if      (c1 == 254u) { c1 = nb; s1 += dn; }
            else if (c2 == 254u) { c2 = nb; s2 += dn; }
            else if (c3 == 254u) { c3 = nb; s3 += dn; }
            else ovf = true;
            rem &= ~en;
        }
        if (rem) ovf = true;
    }

    if (ovf) return slow_vote_bins(rows, x, y, t, bins);

    // argmax with tie -> lowest label (empty slots: s=0 < s0>=3, never win)
    int bs = s0; unsigned bl = cl;
    if (s1 > bs || (s1 == bs && c1 < bl)) { bs = s1; bl = c1; }
    if (s2 > bs || (s2 == bs && c2 < bl)) { bs = s2; bl = c2; }
    if (s3 > bs || (s3 == bs && c3 < bl)) { bs = s3; bl = c3; }
    return (int)bl;
}

// ---------------------------------------------------------------------------
// vote kernel: round-0 proven gather + uniform fast path; slow path is now
// SWAR-in-registers with bins fallback. Grid (7,28,4) x (32,8).
// ---------------------------------------------------------------------------
__global__ __launch_bounds__(256) void vote_kernel(const unsigned char* __restrict__ in,
                                                   unsigned char* __restrict__ out8,
                                                   int* __restrict__ out32) {
    __shared__ unsigned bins[16 * 256];
    const int tx = threadIdx.x, ty = threadIdx.y;
    const int t  = ty * 32 + tx;
    const int x  = blockIdx.x * 32 + tx;
    const int y  = blockIdx.y * 8 + ty;
    const int b  = blockIdx.z;
    const unsigned char* img = in + b * (HH * WW);

    ull rows[7];
    const bool xedge = (blockIdx.x == 0) || (blockIdx.x == (WW / 32 - 1));
    if (!xedge) {
        // interior-x: bytes x-3..x+3 are in-image; 3 aligned dword loads/row
        const unsigned* img32 = (const unsigned*)img;
        const int o0 = x - 3;
#pragma unroll
        for (int dy = -3; dy <= 3; ++dy) {
            int yc = min(max(y + dy, 0), HH - 1);
            int o  = yc * WW + o0;
            int a  = o >> 2;
            int sh = (o & 3) * 8;
            unsigned d0 = img32[a], d1 = img32[a + 1], d2 = img32[a + 2];
            ull lo = ((ull)d1 << 32) | d0;
            ull row = lo >> sh;
            if (sh) row |= (ull)d2 << (64 - sh);
            rows[dy + 3] = row & 0x00FFFFFFFFFFFFFFull;
        }
    } else {
        // x-edge blocks: per-byte clamped gather (proven addressing)
#pragma unroll
        for (int dy = -3; dy <= 3; ++dy) {
            int yc = min(max(y + dy, 0), HH - 1);
            ull row = 0ull;
#pragma unroll
            for (int dx = -3; dx <= 3; ++dx) {
                int xc = min(max(x + dx, 0), WW - 1);
                row |= (ull)img[yc * WW + xc] << (8 * (dx + 3));
            }
            rows[dy + 3] = row;
        }
    }

    const unsigned labc = (unsigned)((rows[3] >> 24) & 255u);   // dy=0, dx=0
    const ull rep = (ull)labc * 0x0001010101010101ull;
    bool uni = true;
#pragma unroll
    for (int k = 0; k < 7; ++k) uni = uni && (rows[k] == rep);

    int best_k;
    if (uni) {
        // all clamped-window bytes == center => every valid neighbor == center
        // => center is the unique positive vote => argmax = center. Exact.
        best_k = (int)labc;
    } else {
        best_k = swar_or_bins(rows, x, y, labc, t, bins);
    }

    int o = (b * HH + y) * WW + x;
    if (out8)  out8[o]  = (unsigned char)best_k;
    if (out32) out32[o] = best_k;
}

// ---------------------------------------------------------------------------
extern "C" void kernel_launch(void* const* d_in, const int* in_sizes, int n_in,
                              void* d_out, int out_size, void* d_ws, size_t ws_size,
                              hipStream_t stream) {
    (void)in_sizes; (void)n_in; (void)out_size; (void)ws_size;
    const float* grad = (const float*)d_in[0];
    int* out = (int*)d_out;
    char* ws = (char*)d_ws;

    int* cv = (int*)(ws);                               // 25088 B
    int* ch = (int*)(ws + 25088);                       // 25088 B
    unsigned char* laW = (unsigned char*)(ws + 50176);  // ping (ws)
    unsigned char* laD = (unsigned char*)d_out;         // pong (inside d_out)

    dp_kernel<<<56, 64, 0, stream>>>(grad, cv, ch);

    dim3 grid(WW / 32, HH / 8, BB), blk(32, 8, 1);
    labvote_kernel<<<grid, blk, 0, stream>>>(cv, ch, laD);        // v1 -> laD
    vote_kernel<<<grid, blk, 0, stream>>>(laD, laW, nullptr);     // v2 -> laW
    vote_kernel<<<grid, blk, 0, stream>>>(laW, laD, nullptr);     // v3 -> laD
    vote_kernel<<<grid, blk, 0, stream>>>(laD, laW, nullptr);     // v4 -> laW
    vote_kernel<<<grid, blk, 0, stream>>>(laW, nullptr, out);     // v5 -> int out
}

// Round 4
// 123.503 us; speedup vs baseline: 4.3281x; 1.0068x over previous
//
#include <hip/hip_runtime.h>
#include <stdint.h>

#define HH 224
#define WW 224
#define BB 4
#define PP 7          // seams per direction
#define SEG 28
#define BW 5
#define MM 11         // 2*BW+1

#define POS_INF_I 0x7F800000

typedef const __attribute__((address_space(1))) unsigned int* gas_ptr;
typedef __attribute__((address_space(3))) unsigned int* las_ptr;
typedef unsigned long long ull;

// map-compose for 11-entry 4-bit-nibble maps packed in u64:  H[i] = F[G[i]]
__device__ inline ull mcompose(ull F, ull G) {
    ull H = 0ull;
#pragma unroll
    for (int i = 0; i < 11; ++i) {
        unsigned g = (unsigned)(G >> (4 * i)) & 15u;
        H |= ((F >> (4 * g)) & 15ull) << (4 * i);
    }
    return H;
}

// ---------------------------------------------------------------------------
// DP kernel (verified absmax 0 — unchanged)
// ---------------------------------------------------------------------------
__global__ __launch_bounds__(64) void dp_kernel(const float* __restrict__ grad,
                                                int* __restrict__ coords_v,
                                                int* __restrict__ coords_h) {
    __shared__ __align__(16) float gseg[225 * 16];

    const int tid = threadIdx.x;
    const int l   = tid & 15;
    const int sid = blockIdx.x;
    const int p   = sid % PP;
    const int dir = (sid / PP) & 1;
    const int b   = sid / (2 * PP);
    const int base = SEG * (p + 1);
    const float* gb = grad + b * (HH * WW);

    {
        const int r  = tid >> 4;
        const int m  = tid & 15;
        const int sS = (dir == 0) ? WW : 1;
        const int sM = (dir == 0) ? 1  : WW;
        const float* src = gb + r * sS + (base - BW + m) * sM;
        const long stepBytes = (long)(4 * sS) * 4;
#pragma unroll 8
        for (int c = 0; c < 56; ++c) {
            __builtin_amdgcn_global_load_lds((gas_ptr)(const void*)src,
                                             (las_ptr)(void*)(&gseg[c * 64]), 4, 0, 0);
            src = (const float*)((const char*)src + stepBytes);
        }
    }
    __syncthreads();

    const float lane_add = (l < MM) ? 0.0f : __int_as_float(POS_INF_I);
    const float* gp = &gseg[l];

    unsigned wreg[16] = {};

#define DP_STEP(gval, ownb, jj_c)                                                       \
    {                                                                                   \
        float v1 = cost;                                                                \
        float v0 = __int_as_float(__builtin_amdgcn_update_dpp(                          \
            POS_INF_I, __float_as_int(cost), 0x111, 0xf, 0xf, false));                  \
        float v2 = __int_as_float(__builtin_amdgcn_update_dpp(                          \
            POS_INF_I, __float_as_int(cost), 0x101, 0xf, 0xf, false));                  \
        bool a01 = (v0 <= v1), a02 = (v0 <= v2), a12 = (v1 <= v2);                      \
        bool aa  = a01 && a02;                                                          \
        unsigned long long A   = __ballot(aa);                                          \
        unsigned long long C12 = __ballot(a12);                                         \
        unsigned long long B0 = ~A & C12;                                               \
        unsigned long long B1 = ~A & ~C12;                                              \
        float mv = aa ? v0 : (a12 ? v1 : v2);                                           \
        cost = mv - (gval) + lane_add;                                                  \
        unsigned wv = (unsigned)(B0 & 0x7FFull) | ((unsigned)(B1 & 0x7FFull) << 11);    \
        wreg[(jj_c)] = (ownb) ? wv : wreg[(jj_c)];                                      \
    }

    float cost = -gp[0] + lane_add;
    float buf[16], c0[16];
#pragma unroll
    for (int k = 0; k < 16; ++k) buf[k] = gp[(1 + k) * 16];
    for (int t = 0; t < 13; ++t) {
        const bool own = (tid == t);
#pragma unroll
        for (int k = 0; k < 16; ++k) c0[k] = buf[k];
#pragma unroll
        for (int k = 0; k < 16; ++k) buf[k] = gp[(16 * (t + 1) + 1 + k) * 16];
#pragma unroll
        for (int k = 0; k < 16; ++k) DP_STEP(c0[k], own, k)
    }
    {
        const bool own = (tid == 13);
#pragma unroll
        for (int k = 0; k < 15; ++k) DP_STEP(buf[k], own, k)
    }
#undef DP_STEP

    float bc = cost;
    int   bi = l;
#pragma unroll
    for (int mask = 1; mask < 16; mask <<= 1) {
        float oc = __shfl_xor(bc, mask, 16);
        int   oi = __shfl_xor(bi, mask, 16);
        if (oc < bc || (oc == bc && oi < bi)) { bc = oc; bi = oi; }
    }
    const int idx_last = bi;

    const int mcnt = (l < 13) ? 16 : ((l == 13) ? 15 : 0);
    const ull IDMAP = 0xA9876543210ull;
    ull L = IDMAP;
#pragma unroll
    for (int jj = 15; jj >= 0; --jj) {
        if (jj < mcnt) {
            unsigned ww = wreg[jj];
            ull M = 0ull;
#pragma unroll
            for (int i = 0; i < MM; ++i) {
                unsigned sel = ((ww >> i) & 1u) + 2u * ((ww >> (11 + i)) & 1u);
                M |= ((ull)(i + (int)sel - 1)) << (4 * i);
            }
            L = mcompose(M, L);
        }
    }
    ull I = L;
#pragma unroll
    for (int d = 1; d < 16; d <<= 1) {
        ull O = __shfl_down(I, d, 16);
        if (l + d < 16) I = mcompose(I, O);
    }
    ull R = __shfl_down(I, 1, 16);
    if (l == 15) R = IDMAP;

    int* cout = (dir == 0) ? coords_v : coords_h;
    if (tid == 15) cout[(b * HH + 223) * PP + p] = base + idx_last - BW;
    if (tid < 16) {
        unsigned v = (unsigned)(R >> (4 * idx_last)) & 15u;
#pragma unroll
        for (int jj = 15; jj >= 0; --jj) {
            if (jj < mcnt) {
                unsigned ww = wreg[jj];
                unsigned sel = ((ww >> v) & 1u) + 2u * ((ww >> (11 + v)) & 1u);
                v = v + sel - 1u;
                cout[(b * HH + (16 * l + jj)) * PP + p] = base + (int)v - BW;
            }
        }
    }
}

// ---------------------------------------------------------------------------
// shared region geometry for labvote/vote: 38x14 clamped label region in LDS
// ---------------------------------------------------------------------------
#define RW 38
#define RH 14
#define RSTR 40   // multiple of 8; RH*RSTR = 560 bytes exactly (gather stays in-bounds)

// ---------------------------------------------------------------------------
// Proven LDS-bins slow path (round-0 logic, verbatim) — the FALLBACK.
// ---------------------------------------------------------------------------
__device__ __forceinline__ int slow_vote_bins(const ull* rows, int x, int y, int t,
                                              unsigned* __restrict__ bins) {
#pragma unroll
    for (int c = 0; c < 16; ++c) bins[c * 256 + t] = 0u;
#pragma unroll
    for (int dy = -3; dy <= 3; ++dy) {
        if ((unsigned)(y + dy) >= (unsigned)HH) continue;
        ull row = rows[dy + 3];
        const int ay = dy < 0 ? -dy : dy;
#pragma unroll
        for (int dx = -3; dx <= 3; ++dx) {
            if ((unsigned)(x + dx) >= (unsigned)WW) continue;
            int lb = (int)((row >> (8 * (dx + 3))) & 255u);
            const int ax = dx < 0 ? -dx : dx;
            const int d = ay > ax ? ay : ax;
            const unsigned wgt = (d <= 1) ? 3u : (unsigned)(4 - d);
            atomicAdd(&bins[(lb >> 2) * 256 + t], wgt << ((lb & 3) * 8));
        }
    }
    int best_s = 0, best_k = 0;
#pragma unroll
    for (int c = 0; c < 16; ++c) {
        unsigned wd = bins[c * 256 + t];
        if (wd) {
#pragma unroll
            for (int q = 0; q < 4; ++q) {
                int s = (int)((wd >> (q * 8)) & 255u);
                if (s > best_s) { best_s = s; best_k = c * 4 + q; }
            }
        }
    }
    return best_k;
}

// ---------------------------------------------------------------------------
// Register-only SWAR slow path (verified absmax 0 in round 3 — unchanged).
// ---------------------------------------------------------------------------
#define SW_K1   0x0001010101010101ull
#define SW_HI7  0x0080808080808080ull
#define SW_LO7  0x007F7F7F7F7F7F7Full
#define SW_W1   0x0001020303030201ull   /* rows |dy|<=1: [1,2,3,3,3,2,1] */
#define SW_W2   0x0001020202020201ull   /* rows |dy|==2: [1,2,2,2,2,2,1] */

__device__ __forceinline__ ull sw_zm(ull xv) {
    return (~(((xv & SW_LO7) + SW_LO7) | xv)) & SW_HI7;
}
__device__ __forceinline__ int sw_dotm(ull m, ull W) {
    return (int)((((m >> 7) * W) >> 48) & 0xFFull);
}

__device__ __forceinline__ int swar_or_bins(const ull* rows, int x, int y,
                                            unsigned cl, int t,
                                            unsigned* __restrict__ bins) {
    // x-validity: marker at byte dx iff 0 <= x+dx-3 < WW
    ull vmx = SW_HI7;
    if (x < 3)   vmx &= (~0ull) << (8 * (3 - x));
    if (x > 220) vmx &= (1ull << (8 * (227 - x))) - 1ull;

    unsigned c1 = 254u, c2 = 254u, c3 = 254u;   // 254 = empty slot (never a label)
    int s0 = 0, s1 = 0, s2 = 0, s3 = 0;
    bool ovf = false;
    const ull rep0 = (ull)cl * SW_K1;

#pragma unroll
    for (int r = 0; r < 7; ++r) {
        if ((unsigned)(y + r - 3) >= (unsigned)HH) continue;
        const ull row = rows[r];
        const int ay   = r < 3 ? 3 - r : r - 3;        // compile-time per r
        const bool POPC = (ay == 3);                    // weight row all-ones
        const ull W    = (ay <= 1) ? SW_W1 : SW_W2;

        ull e0 = sw_zm(row ^ rep0) & vmx;
        ull e1 = sw_zm(row ^ ((ull)c1 * SW_K1)) & vmx;
        ull e2 = sw_zm(row ^ ((ull)c2 * SW_K1)) & vmx;
        ull e3 = sw_zm(row ^ ((ull)c3 * SW_K1)) & vmx;
        s0 += POPC ? __popcll(e0) : sw_dotm(e0, W);
        s1 += POPC ? __popcll(e1) : sw_dotm(e1, W);
        s2 += POPC ? __popcll(e2) : sw_dotm(e2, W);
        s3 += POPC ? __popcll(e3) : sw_dotm(e3, W);

        ull rem = vmx & ~(e0 | e1 | e2 | e3);
        for (int it = 0; it < 3 && rem; ++it) {
            int pos = (int)__builtin_ctzll(rem);        // marker bit = 8k+7
            unsigned nb = (unsigned)((row >> (pos - 7)) & 255u);
            ull en = sw_zm(row ^ ((ull)nb * SW_K1)) & vmx;
            int dn = POPC ? __popcll(en) : sw_dotm(en, W);
            if      (c1 == 254u) { c1 = nb; s1 += dn; }
            else if (c2 == 254u) { c2 = nb; s2 += dn; }
            else if (c3 == 254u) { c3 = nb; s3 += dn; }
            else ovf = true;
            rem &= ~en;
        }
        if (rem) ovf = true;
    }

    if (ovf) return slow_vote_bins(rows, x, y, t, bins);

    int bs = s0; unsigned bl = cl;
    if (s1 > bs || (s1 == bs && c1 < bl)) { bs = s1; bl = c1; }
    if (s2 > bs || (s2 == bs && c2 < bl)) { bs = s2; bl = c2; }
    if (s3 > bs || (s3 == bs && c3 < bl)) { bs = s3; bl = c3; }
    return (int)bl;
}

// ---------------------------------------------------------------------------
// 7-row window gather from the LDS label region. Thread (tx,ty) window rows
// are region rows ty..ty+6, cols tx..tx+6 (region origin = tile origin -3,
// clamped). Unaligned 8B read = two aligned b64 + funnel shift; byte 7 masked.
// Max address: (13*40+31)&~7 + 8 = 552..559 < 560 — in bounds.
// ---------------------------------------------------------------------------
__device__ __forceinline__ void gather_rows_lds(const unsigned char* lab,
                                                int tx, int ty, ull* rows) {
#pragma unroll
    for (int r = 0; r < 7; ++r) {
        int o  = (ty + r) * RSTR + tx;
        int a8 = o & ~7;
        int sh = (o & 7) * 8;
        ull lo = *reinterpret_cast<const ull*>(lab + a8);
        ull hi = *reinterpret_cast<const ull*>(lab + a8 + 8);
        ull row = lo >> sh;
        if (sh) row |= hi << (64 - sh);
        rows[r] = row & 0x00FFFFFFFFFFFFFFull;
    }
}

// ---------------------------------------------------------------------------
// labvote: analytic initial labels for the CLAMPED 38x14 region (clamped
// coords = labels of clamped pixels, matching proven clamped-gather
// semantics), then vote iteration 1 via uniform/SWAR/bins. Grid (7,28,4)x(32,8).
// ---------------------------------------------------------------------------
__global__ __launch_bounds__(256) void labvote_kernel(const int* __restrict__ cv,
                                                      const int* __restrict__ ch,
                                                      unsigned char* __restrict__ out8) {
    __shared__ __align__(8) unsigned char lab[RH * RSTR];
    __shared__ unsigned bins[16 * 256];
    const int tx = threadIdx.x, ty = threadIdx.y;
    const int t  = ty * 32 + tx;
    const int b  = blockIdx.z;
    const int GX0 = blockIdx.x * 32, GY0 = blockIdx.y * 8;

    for (int idx = t; idx < RW * RH; idx += 256) {
        int j = idx / RW, i = idx - j * RW;
        int gxc = min(max(GX0 - 3 + i, 0), WW - 1);
        int gyc = min(max(GY0 - 3 + j, 0), HH - 1);
        const int* cvp = cv + (b * HH + gyc) * PP;
        const int* chp = ch + (b * WW + gxc) * PP;
        int v = 0, h = 0;
#pragma unroll
        for (int q = 0; q < PP; ++q) { v += (cvp[q] <= gxc); h += (chp[q] <= gyc); }
        lab[j * RSTR + i] = (unsigned char)(v + 8 * h);
    }
    __syncthreads();

    const int x = GX0 + tx, y = GY0 + ty;
    ull rows[7];
    gather_rows_lds(lab, tx, ty, rows);

    const unsigned labc = (unsigned)((rows[3] >> 24) & 255u);
    const ull rep = (ull)labc * SW_K1;
    bool uni = true;
#pragma unroll
    for (int k = 0; k < 7; ++k) uni = uni && (rows[k] == rep);

    int best_k = uni ? (int)labc : swar_or_bins(rows, x, y, labc, t, bins);
    out8[(b * HH + y) * WW + x] = (unsigned char)best_k;
}

// ---------------------------------------------------------------------------
// vote kernel v4: LDS-staged clamped 38x14 region (532 byte loads/block
// instead of 21 dword loads/thread), block-uniform early-out, then per-pixel
// uniform fast path / SWAR / bins fallback. Grid (7,28,4) x (32,8).
// ---------------------------------------------------------------------------
__global__ __launch_bounds__(256) void vote_kernel(const unsigned char* __restrict__ in,
                                                   unsigned char* __restrict__ out8,
                                                   int* __restrict__ out32) {
    __shared__ __align__(8) unsigned char lab[RH * RSTR];
    __shared__ unsigned bins[16 * 256];
    __shared__ int blkuni;
    const int tx = threadIdx.x, ty = threadIdx.y;
    const int t  = ty * 32 + tx;
    const int x  = blockIdx.x * 32 + tx;
    const int y  = blockIdx.y * 8 + ty;
    const int b  = blockIdx.z;
    const int GX0 = blockIdx.x * 32, GY0 = blockIdx.y * 8;
    const unsigned char* img = in + b * (HH * WW);

    if (t == 0) blkuni = 1;
    for (int idx = t; idx < RW * RH; idx += 256) {
        int j = idx / RW, i = idx - j * RW;
        int gxc = min(max(GX0 - 3 + i, 0), WW - 1);
        int gyc = min(max(GY0 - 3 + j, 0), HH - 1);
        lab[j * RSTR + i] = img[gyc * WW + gxc];
    }
    __syncthreads();

    // block-uniform early-out: whole clamped region one label => every pixel's
    // clamped window == its center => argmax = center for all (exact).
    {
        const unsigned char ref = lab[0];
        int ok = 1;
        for (int idx = t; idx < RW * RH; idx += 256) {
            int j = idx / RW, i = idx - j * RW;
            ok &= (lab[j * RSTR + i] == ref);
        }
        if (!ok) blkuni = 0;
        __syncthreads();
        if (blkuni) {
            int o = (b * HH + y) * WW + x;
            if (out8)  out8[o]  = ref;
            if (out32) out32[o] = (int)ref;
            return;
        }
    }

    ull rows[7];
    gather_rows_lds(lab, tx, ty, rows);

    const unsigned labc = (unsigned)((rows[3] >> 24) & 255u);
    const ull rep = (ull)labc * SW_K1;
    bool uni = true;
#pragma unroll
    for (int k = 0; k < 7; ++k) uni = uni && (rows[k] == rep);

    int best_k = uni ? (int)labc : swar_or_bins(rows, x, y, labc, t, bins);

    int o = (b * HH + y) * WW + x;
    if (out8)  out8[o]  = (unsigned char)best_k;
    if (out32) out32[o] = best_k;
}

// ---------------------------------------------------------------------------
extern "C" void kernel_launch(void* const* d_in, const int* in_sizes, int n_in,
                              void* d_out, int out_size, void* d_ws, size_t ws_size,
                              hipStream_t stream) {
    (void)in_sizes; (void)n_in; (void)out_size; (void)ws_size;
    const float* grad = (const float*)d_in[0];
    int* out = (int*)d_out;
    char* ws = (char*)d_ws;

    int* cv = (int*)(ws);                               // 25088 B
    int* ch = (int*)(ws + 25088);                       // 25088 B
    unsigned char* laW = (unsigned char*)(ws + 50176);  // ping (ws)
    unsigned char* laD = (unsigned char*)d_out;         // pong (inside d_out)

    dp_kernel<<<56, 64, 0, stream>>>(grad, cv, ch);

    dim3 grid(WW / 32, HH / 8, BB), blk(32, 8, 1);
    labvote_kernel<<<grid, blk, 0, stream>>>(cv, ch, laD);        // v1 -> laD
    vote_kernel<<<grid, blk, 0, stream>>>(laD, laW, nullptr);     // v2 -> laW
    vote_kernel<<<grid, blk, 0, stream>>>(laW, laD, nullptr);     // v3 -> laD
    vote_kernel<<<grid, blk, 0, stream>>>(laD, laW, nullptr);     // v4 -> laW
    vote_kernel<<<grid, blk, 0, stream>>>(laW, nullptr, out);     // v5 -> int out
}